// Round 10
// baseline (1907.603 us; speedup 1.0000x reference)
//
#include <hip/hip_runtime.h>
#include <hip/hip_bf16.h>
#include <hip/hip_fp16.h>

#define NN 100000
#define EE 3200000
#define FF 128
#define F2 256
#define VV 8
#define LL 3
#define EPSV 1e-5f
#define NB 98        // idiv(NN,1024)
#define NCHK 8       // feature chunks (16 features each)
#define NTIL 3125    // NN / 32

static inline int idiv(int a, int b){ return (a + b - 1) / b; }

// ---------- degree count ----------
__global__ void k_deg(const int* __restrict__ dst, int* __restrict__ edeg){
  int stride = gridDim.x * 256;
  for (int e = blockIdx.x * 256 + threadIdx.x; e < EE; e += stride)
    atomicAdd(&edeg[dst[e]], 1);
}

// ---------- exclusive scan of edeg -> offs (+ dinv) ----------
__global__ void k_scanA(const int* __restrict__ edeg, int* __restrict__ offs,
                        int* __restrict__ bsum, float* __restrict__ dinv){
  __shared__ int s[1024];
  int t = threadIdx.x;
  int i = blockIdx.x * 1024 + t;
  int v = (i < NN) ? edeg[i] : 0;
  if (i < NN) dinv[i] = rsqrtf((float)(v + 1));
  int x = v;
  s[t] = x; __syncthreads();
  for (int d = 1; d < 1024; d <<= 1){
    int y = (t >= d) ? s[t - d] : 0;
    __syncthreads();
    x += y; s[t] = x;
    __syncthreads();
  }
  if (i < NN) offs[i] = x - v;
  if (t == 1023) bsum[blockIdx.x] = x;
}

__global__ void k_scanB(int* __restrict__ bsum){
  __shared__ int s[128];
  int t = threadIdx.x;
  s[t] = (t < NB) ? bsum[t] : 0;
  __syncthreads();
  if (t == 0){
    int run = 0;
    for (int k = 0; k < NB; ++k){ int tmp = s[k]; s[k] = run; run += tmp; }
  }
  __syncthreads();
  if (t < NB) bsum[t] = s[t];
}

__global__ void k_scanC(int* __restrict__ offs, const int* __restrict__ bsum,
                        int* __restrict__ cursor){
  int i = blockIdx.x * 256 + threadIdx.x;
  if (i < NN){
    int o = offs[i] + bsum[i >> 10];
    offs[i] = o;
    cursor[i] = o;
  }
  if (i == 0) offs[NN] = EE;
}

// ---------- counting-sort scatter ----------
__global__ void k_scatter(const int* __restrict__ src, const int* __restrict__ dst,
                          int* __restrict__ cursor, int* __restrict__ ssorted){
  int stride = gridDim.x * 256;
  for (int e = blockIdx.x * 256 + threadIdx.x; e < EE; e += stride){
    int d = dst[e];
    int pos = atomicAdd(&cursor[d], 1);
    ssorted[pos] = src[e];
  }
}

// ---------- mask dtype detect: 1 = bool(1B), 0 = int32 ----------
__global__ void k_maskdetect(const unsigned char* __restrict__ m, int* __restrict__ flag){
  int any = 0;
  for (int t = threadIdx.x; t < 4096; t += 256)
    if ((t & 3) && m[t]) any = 1;
  if (any) atomicOr(flag, 1);
}

// ---------- hlb[c][n][16] = fp16( (relu(bn(in[n]))@W + (sum_v vn)@W) * dinv[n] ) ----------
__launch_bounds__(256)
__global__ void k_matmul(const float* __restrict__ in, const float* __restrict__ W,
                         const float* __restrict__ vn, const float* __restrict__ dinv,
                         const float* __restrict__ ss, int hasbn,
                         uint2* __restrict__ hlb){
  __shared__ float Ws[FF * FF];     // 64 KB
  __shared__ float As[32 * FF];     // 16 KB
  __shared__ float vs[FF];
  __shared__ float rv[FF];
  __shared__ float scs[FF], shs[FF];
  int tid = threadIdx.x;
  for (int t = tid; t < FF * FF; t += 256) Ws[t] = W[t];
  if (tid < FF){
    float s = 0.f;
    for (int v = 0; v < VV; ++v) s += vn[v * FF + tid];
    vs[tid] = s;
    scs[tid] = hasbn ? ss[tid] : 1.0f;
    shs[tid] = hasbn ? ss[FF + tid] : 0.0f;
  }
  __syncthreads();
  if (tid < FF){
    float a = 0.f;
    for (int k = 0; k < FF; ++k) a += vs[k] * Ws[k * FF + tid];
    rv[tid] = a;
  }
  __syncthreads();
  int g = tid >> 5;                 // 0..7 row group
  int c = tid & 31;                 // col quad (features 4c..4c+3)
  int chk = c >> 2;                 // feature chunk
  int cw  = c & 3;                  // uint2 slot within chunk row
  float4 rvv = ((const float4*)rv)[c];
  for (int base = blockIdx.x * 32; base < NN; base += gridDim.x * 32){
    const float4* in4 = (const float4*)(in + (size_t)base * FF);
    for (int i = tid; i < 32 * 32; i += 256){
      float4 vv = in4[i];
      if (hasbn){
        int cq = (i & 31) * 4;
        vv.x = fmaxf(fmaf(vv.x, scs[cq + 0], shs[cq + 0]), 0.f);
        vv.y = fmaxf(fmaf(vv.y, scs[cq + 1], shs[cq + 1]), 0.f);
        vv.z = fmaxf(fmaf(vv.z, scs[cq + 2], shs[cq + 2]), 0.f);
        vv.w = fmaxf(fmaf(vv.w, scs[cq + 3], shs[cq + 3]), 0.f);
      }
      ((float4*)As)[i] = vv;
    }
    __syncthreads();
    float4 a0 = rvv, a1 = rvv, a2 = rvv, a3 = rvv;
    #pragma unroll 4
    for (int k = 0; k < FF; ++k){
      float4 wv = ((const float4*)Ws)[k * 32 + c];
      float x0 = As[(g +  0) * FF + k];
      float x1 = As[(g +  8) * FF + k];
      float x2 = As[(g + 16) * FF + k];
      float x3 = As[(g + 24) * FF + k];
      a0.x += x0 * wv.x; a0.y += x0 * wv.y; a0.z += x0 * wv.z; a0.w += x0 * wv.w;
      a1.x += x1 * wv.x; a1.y += x1 * wv.y; a1.z += x1 * wv.z; a1.w += x1 * wv.w;
      a2.x += x2 * wv.x; a2.y += x2 * wv.y; a2.z += x2 * wv.z; a2.w += x2 * wv.w;
      a3.x += x3 * wv.x; a3.y += x3 * wv.y; a3.z += x3 * wv.z; a3.w += x3 * wv.w;
    }
    #pragma unroll
    for (int rr = 0; rr < 4; ++rr){
      float4 a = (rr == 0) ? a0 : (rr == 1) ? a1 : (rr == 2) ? a2 : a3;
      int r = base + g + 8 * rr;
      float d = dinv[r];
      __half2 h01 = __floats2half2_rn(a.x * d, a.y * d);
      __half2 h23 = __floats2half2_rn(a.z * d, a.w * d);
      uint2 pk;
      pk.x = *reinterpret_cast<unsigned int*>(&h01);
      pk.y = *reinterpret_cast<unsigned int*>(&h23);
      hlb[((size_t)chk * NN + r) * 4 + cw] = pk;   // chunk-major
    }
    __syncthreads();
  }
}

// ---------- feature-chunked CSR gather: grid (NTIL, NCHK) ----------
// wave = 8 nodes x 8 lanes; chunk table = 3.2MB -> L2-resident per XCD
__launch_bounds__(256)
__global__ void k_gather(const unsigned int* __restrict__ hlb, const float* __restrict__ dinv,
                         const int* __restrict__ offs, const int* __restrict__ ssorted,
                         float2* __restrict__ agg2){
  int tid = threadIdx.x;
  int w = tid >> 6;
  int lane = tid & 63;
  int sub = lane >> 3;
  int word = lane & 7;
  int c8 = blockIdx.y;
  const unsigned int* hc = hlb + (size_t)c8 * NN * 8;
  int n = blockIdx.x * 32 + (w << 3) + sub;
  int off0 = offs[n], off1 = offs[n + 1];
  unsigned int sv = hc[n * 8 + word];
  float2 acc = __half22float2(*reinterpret_cast<__half2*>(&sv));
  #pragma unroll 4
  for (int e = off0; e < off1; ++e){
    int s = ssorted[e];
    unsigned int v = hc[s * 8 + word];
    float2 f = __half22float2(*reinterpret_cast<__half2*>(&v));
    acc.x += f.x; acc.y += f.y;
  }
  float dv = dinv[n];
  agg2[(size_t)n * 64 + c8 * 8 + word] = make_float2(acc.x * dv, acc.y * dv);
}

// ---------- BN column stats over agg (streaming) ----------
__launch_bounds__(256)
__global__ void k_stats(const float4* __restrict__ agg4, float* __restrict__ stats){
  int tid = threadIdx.x;
  int c = tid & 31;                 // col quad
  int r = (blockIdx.x * 256 + tid) >> 5;
  int rs = (gridDim.x * 256) >> 5;
  float4 s = {0,0,0,0}, q = {0,0,0,0};
  for (; r < NN; r += rs){
    float4 v = agg4[(size_t)r * 32 + c];
    s.x += v.x; s.y += v.y; s.z += v.z; s.w += v.w;
    q.x += v.x*v.x; q.y += v.y*v.y; q.z += v.z*v.z; q.w += v.w*v.w;
  }
  __shared__ float4 sm[256], qm[256];
  sm[tid] = s; qm[tid] = q;
  __syncthreads();
  if (tid < 32){
    float4 ts = sm[tid], tq = qm[tid];
    #pragma unroll
    for (int k = 1; k < 8; ++k){
      float4 a = sm[k * 32 + tid], b = qm[k * 32 + tid];
      ts.x += a.x; ts.y += a.y; ts.z += a.z; ts.w += a.w;
      tq.x += b.x; tq.y += b.y; tq.z += b.z; tq.w += b.w;
    }
    atomicAdd(&stats[4 * tid + 0], ts.x);
    atomicAdd(&stats[4 * tid + 1], ts.y);
    atomicAdd(&stats[4 * tid + 2], ts.z);
    atomicAdd(&stats[4 * tid + 3], ts.w);
    atomicAdd(&stats[FF + 4 * tid + 0], tq.x);
    atomicAdd(&stats[FF + 4 * tid + 1], tq.y);
    atomicAdd(&stats[FF + 4 * tid + 2], tq.z);
    atomicAdd(&stats[FF + 4 * tid + 3], tq.w);
  }
}

// ---------- stats -> scale/shift ----------
__global__ void k_bnfin(const float* __restrict__ stats, const float* __restrict__ g,
                        const float* __restrict__ b, float* __restrict__ ss){
  int j = threadIdx.x;   // 128
  float mean = stats[j] * (1.0f / NN);
  float var  = stats[FF + j] * (1.0f / NN) - mean * mean;
  float sc = rsqrtf(var + EPSV) * g[j];
  ss[j] = sc;
  ss[FF + j] = b[j] - mean * sc;
}

// ---------- BN finalize + apply (final layer, no relu) ----------
__launch_bounds__(256)
__global__ void k_bnapply(float4* __restrict__ h, const float* __restrict__ stats,
                          const float* __restrict__ g, const float* __restrict__ b){
  __shared__ float ss[2 * FF];
  int tid = threadIdx.x;
  if (tid < FF){
    float mean = stats[tid] * (1.0f / NN);
    float var  = stats[FF + tid] * (1.0f / NN) - mean * mean;
    float sc = rsqrtf(var + EPSV) * g[tid];
    ss[tid] = sc;
    ss[FF + tid] = b[tid] - mean * sc;
  }
  __syncthreads();
  int n4 = NN * FF / 4;
  int stride = gridDim.x * 256;
  for (int i = blockIdx.x * 256 + tid; i < n4; i += stride){
    int c = (i & 31) * 4;
    float4 v = h[i];
    float4 sc = *(const float4*)&ss[c];
    float4 sh = *(const float4*)&ss[FF + c];
    v.x = v.x * sc.x + sh.x;
    v.y = v.y * sc.y + sh.y;
    v.z = v.z * sc.z + sh.z;
    v.w = v.w * sc.w + sh.w;
    h[i] = v;
  }
}

// ---------- pooled[v] = sum_{n: mask[v][n]} relu(bn(emb[n])) ----------
__global__ void k_pool(const float* __restrict__ emb, const unsigned char* __restrict__ m8,
                       const int* __restrict__ m32, const int* __restrict__ flag,
                       const float* __restrict__ ss, int hasbn,
                       float* __restrict__ pooled){
  int isb = *flag;
  int tid = blockIdx.x * 256 + threadIdx.x;
  int j = tid & 127;
  int r = tid >> 7;
  int rs = (gridDim.x * 256) >> 7;
  float sc = hasbn ? ss[j] : 1.0f;
  float sh = hasbn ? ss[FF + j] : 0.0f;
  float acc[VV];
  #pragma unroll
  for (int v = 0; v < VV; ++v) acc[v] = 0.f;
  for (; r < NN; r += rs){
    float xv = emb[r * FF + j];
    xv = fmaf(xv, sc, sh);
    if (hasbn) xv = fmaxf(xv, 0.f);
    #pragma unroll
    for (int v = 0; v < VV; ++v){
      int mv = isb ? (int)m8[v * NN + r] : m32[v * NN + r];
      if (mv) acc[v] += xv;
    }
  }
  #pragma unroll
  for (int v = 0; v < VV; ++v) atomicAdd(&pooled[v * FF + j], acc[v]);
}

// ---------- per-VN MLP ----------
__device__ __forceinline__ float blockSum(float x, float* red, int tid){
  red[tid] = x; __syncthreads();
  #pragma unroll
  for (int s = 128; s >= 1; s >>= 1){
    if (tid < s) red[tid] += red[tid + s];
    __syncthreads();
  }
  float r = red[0];
  __syncthreads();
  return r;
}

__launch_bounds__(256)
__global__ void k_vnmlp(const float* __restrict__ pooled, const float* __restrict__ vnin,
                        const float* __restrict__ W1, const float* __restrict__ b1,
                        const float* __restrict__ g1, const float* __restrict__ bb1,
                        const float* __restrict__ W2, const float* __restrict__ b2,
                        const float* __restrict__ g2, const float* __restrict__ bb2,
                        float* __restrict__ vnout){
  int v = blockIdx.x;
  int tid = threadIdx.x;
  __shared__ float tmp_s[FF];
  __shared__ float h1_s[F2];
  __shared__ float red[256];
  if (tid < FF) tmp_s[tid] = pooled[v * FF + tid] + vnin[v * FF + tid];
  __syncthreads();
  const float* W1v = W1 + (size_t)v * FF * F2;
  float acc = b1[v * F2 + tid];
  for (int k = 0; k < FF; ++k) acc += tmp_s[k] * W1v[k * F2 + tid];
  acc = fmaxf(acc, 0.f);
  float sum = blockSum(acc, red, tid);
  float sq  = blockSum(acc * acc, red, tid);
  float mean = sum * (1.f / F2);
  float var  = sq * (1.f / F2) - mean * mean;
  float y = (acc - mean) * rsqrtf(var + EPSV) * g1[v * F2 + tid] + bb1[v * F2 + tid];
  h1_s[tid] = y;
  __syncthreads();
  const float* W2v = W2 + (size_t)v * F2 * FF;
  float h2 = 0.f;
  if (tid < FF){
    float a2 = b2[v * FF + tid];
    for (int k = 0; k < F2; ++k) a2 += h1_s[k] * W2v[k * FF + tid];
    h2 = fmaxf(a2, 0.f);
  }
  float sum2 = blockSum((tid < FF) ? h2 : 0.f, red, tid);
  float sq2  = blockSum((tid < FF) ? h2 * h2 : 0.f, red, tid);
  float mean2 = sum2 * (1.f / FF);
  float var2  = sq2 * (1.f / FF) - mean2 * mean2;
  if (tid < FF)
    vnout[v * FF + tid] = (h2 - mean2) * rsqrtf(var2 + EPSV) * g2[v * FF + tid]
                          + bb2[v * FF + tid];
}

extern "C" void kernel_launch(void* const* d_in, const int* in_sizes, int n_in,
                              void* d_out, int out_size, void* d_ws, size_t ws_size,
                              hipStream_t stream){
  const float* x        = (const float*)d_in[0];
  const int*   ei       = (const int*)d_in[1];
  const unsigned char* vmask8 = (const unsigned char*)d_in[2];
  const int*   vmask32  = (const int*)d_in[2];
  const float* Wc       = (const float*)d_in[3];
  const float* bn_g     = (const float*)d_in[5];
  const float* bn_b     = (const float*)d_in[6];
  const float* vn_embed = (const float*)d_in[7];
  const float* mlp_W1   = (const float*)d_in[8];
  const float* mlp_b1   = (const float*)d_in[9];
  const float* ln1_g    = (const float*)d_in[10];
  const float* ln1_b    = (const float*)d_in[11];
  const float* mlp_W2   = (const float*)d_in[12];
  const float* mlp_b2   = (const float*)d_in[13];
  const float* ln2_g    = (const float*)d_in[14];
  const float* ln2_b    = (const float*)d_in[15];
  float* out = (float*)d_out;

  unsigned int* hlb = (unsigned int*)d_ws;               // NCHK*N*8 u32 = 25.6MB (chunk-major)
  float* bufB    = (float*)(hlb + (size_t)NN * 64);      // N*F f32
  int*   ssorted = (int*)(bufB + (size_t)NN * FF);       // E
  int*   offs    = ssorted + EE;                         // N+1
  int*   cursor  = offs + NN + 1;                        // N
  int*   edeg    = cursor + NN;                          // N
  int*   bsum    = edeg + NN;                            // 128
  float* dinv    = (float*)(bsum + 128);                 // N
  float* stats   = dinv + NN;                            // 2F
  float* ssA     = stats + 2 * FF;                       // 2F
  float* ssB     = ssA + 2 * FF;                         // 2F
  float* pooled  = ssB + 2 * FF;                         // V*F
  float* vnA     = pooled + VV * FF;                     // V*F
  float* vnB     = vnA + VV * FF;                        // V*F
  int*   mflag   = (int*)(vnB + VV * FF);                // 1

  const int* esrc = ei;
  const int* edst = ei + EE;

  // ----- CSR build -----
  hipMemsetAsync(edeg, 0, NN * sizeof(int), stream);
  k_deg<<<1024, 256, 0, stream>>>(edst, edeg);
  k_scanA<<<NB, 1024, 0, stream>>>(edeg, offs, bsum, dinv);
  k_scanB<<<1, 128, 0, stream>>>(bsum);
  k_scanC<<<idiv(NN, 256), 256, 0, stream>>>(offs, bsum, cursor);
  k_scatter<<<2048, 256, 0, stream>>>(esrc, edst, cursor, ssorted);

  hipMemsetAsync(mflag, 0, sizeof(int), stream);
  k_maskdetect<<<1, 256, 0, stream>>>(vmask8, mflag);

  const float* vncur = vn_embed;
  const float* embin = x;
  float* ssbufs[2] = {ssA, ssB};
  const float* sscur = nullptr;
  float* vnbufs[2] = {vnA, vnB};

  for (int l = 0; l < LL; ++l){
    float* agg = (l < LL - 1) ? bufB : out;
    const float* Wl = Wc + (size_t)l * FF * FF;
    int hasbn = (l > 0) ? 1 : 0;

    k_matmul<<<1024, 256, 0, stream>>>(embin, Wl, vncur, dinv, sscur, hasbn, (uint2*)hlb);

    if (l < LL - 1){
      hipMemsetAsync(pooled, 0, VV * FF * sizeof(float), stream);
      k_pool<<<1024, 256, 0, stream>>>(embin, vmask8, vmask32, mflag, sscur, hasbn, pooled);
    }

    k_gather<<<dim3(NTIL, NCHK), 256, 0, stream>>>(hlb, dinv, offs, ssorted, (float2*)agg);

    hipMemsetAsync(stats, 0, 2 * FF * sizeof(float), stream);
    k_stats<<<1024, 256, 0, stream>>>((const float4*)agg, stats);

    if (l < LL - 1){
      k_bnfin<<<1, 128, 0, stream>>>(stats, bn_g + l * FF, bn_b + l * FF, ssbufs[l]);
      k_vnmlp<<<VV, 256, 0, stream>>>(pooled, vncur,
          mlp_W1 + (size_t)l * VV * FF * F2, mlp_b1 + (size_t)l * VV * F2,
          ln1_g + (size_t)l * VV * F2, ln1_b + (size_t)l * VV * F2,
          mlp_W2 + (size_t)l * VV * F2 * FF, mlp_b2 + (size_t)l * VV * FF,
          ln2_g + (size_t)l * VV * FF, ln2_b + (size_t)l * VV * FF,
          vnbufs[l]);
      vncur = vnbufs[l];
      sscur = ssbufs[l];
      embin = agg;
    } else {
      k_bnapply<<<1024, 256, 0, stream>>>((float4*)out, stats, bn_g + l * FF, bn_b + l * FF);
    }
  }
}

// Round 11
// 1441.854 us; speedup vs baseline: 1.3230x; 1.3230x over previous
//
#include <hip/hip_runtime.h>
#include <hip/hip_bf16.h>
#include <hip/hip_fp16.h>

#define NN 100000
#define EE 3200000
#define FF 128
#define F2 256
#define VV 8
#define LL 3
#define EPSV 1e-5f
#define NB 98        // idiv(NN,1024)
#define NTILES 3125  // NN/32

typedef _Float16 f16x8 __attribute__((ext_vector_type(8)));
typedef float f32x4 __attribute__((ext_vector_type(4)));

static inline int idiv(int a, int b){ return (a + b - 1) / b; }

// ---------- degree count ----------
__global__ void k_deg(const int* __restrict__ dst, int* __restrict__ edeg){
  int stride = gridDim.x * 256;
  for (int e = blockIdx.x * 256 + threadIdx.x; e < EE; e += stride)
    atomicAdd(&edeg[dst[e]], 1);
}

// ---------- exclusive scan of edeg -> offs (+ dinv) ----------
__global__ void k_scanA(const int* __restrict__ edeg, int* __restrict__ offs,
                        int* __restrict__ bsum, float* __restrict__ dinv){
  __shared__ int s[1024];
  int t = threadIdx.x;
  int i = blockIdx.x * 1024 + t;
  int v = (i < NN) ? edeg[i] : 0;
  if (i < NN) dinv[i] = rsqrtf((float)(v + 1));
  int x = v;
  s[t] = x; __syncthreads();
  for (int d = 1; d < 1024; d <<= 1){
    int y = (t >= d) ? s[t - d] : 0;
    __syncthreads();
    x += y; s[t] = x;
    __syncthreads();
  }
  if (i < NN) offs[i] = x - v;
  if (t == 1023) bsum[blockIdx.x] = x;
}

__global__ void k_scanB(int* __restrict__ bsum){
  __shared__ int s[128];
  int t = threadIdx.x;
  s[t] = (t < NB) ? bsum[t] : 0;
  __syncthreads();
  if (t == 0){
    int run = 0;
    for (int k = 0; k < NB; ++k){ int tmp = s[k]; s[k] = run; run += tmp; }
  }
  __syncthreads();
  if (t < NB) bsum[t] = s[t];
}

__global__ void k_scanC(int* __restrict__ offs, const int* __restrict__ bsum,
                        int* __restrict__ cursor){
  int i = blockIdx.x * 256 + threadIdx.x;
  if (i < NN){
    int o = offs[i] + bsum[i >> 10];
    offs[i] = o;
    cursor[i] = o;
  }
  if (i == 0) offs[NN] = EE;
}

// ---------- counting-sort scatter ----------
__global__ void k_scatter(const int* __restrict__ src, const int* __restrict__ dst,
                          int* __restrict__ cursor, int* __restrict__ ssorted){
  int stride = gridDim.x * 256;
  for (int e = blockIdx.x * 256 + threadIdx.x; e < EE; e += stride){
    int d = dst[e];
    int pos = atomicAdd(&cursor[d], 1);
    ssorted[pos] = src[e];
  }
}

// ---------- mask dtype detect: 1 = bool(1B), 0 = int32 ----------
__global__ void k_maskdetect(const unsigned char* __restrict__ m, int* __restrict__ flag){
  int any = 0;
  for (int t = threadIdx.x; t < 4096; t += 256)
    if ((t & 3) && m[t]) any = 1;
  if (any) atomicOr(flag, 1);
}

// ---------- MFMA matmul: hlb[n] = fp16( (relu(bn(in[n]))@W + (sum_v vn)@W) * dinv[n] )
// tile 32 rows x 128 cols; 4 waves; wave w owns col-tiles {2w, 2w+1}; K=128 in 4 chunks of 32.
__launch_bounds__(256)
__global__ void k_matmul(const float* __restrict__ in, const float* __restrict__ W,
                         const float* __restrict__ vn, const float* __restrict__ dinv,
                         const float* __restrict__ ss, int hasbn,
                         uint2* __restrict__ hlb){
  __shared__ _Float16 As[32 * 136];   // 8.7 KB, pad 136 (2-way bank alias only)
  __shared__ float   Cs[32 * 132];    // 16.9 KB
  __shared__ float vs[FF], rv[FF], scs[FF], shs[FF];
  int tid = threadIdx.x, lane = tid & 63, w = tid >> 6;
  if (tid < FF){
    float s = 0.f;
    for (int v = 0; v < VV; ++v) s += vn[v * FF + tid];
    vs[tid] = s;
    scs[tid] = hasbn ? ss[tid] : 1.0f;
    shs[tid] = hasbn ? ss[FF + tid] : 0.0f;
  }
  __syncthreads();
  if (tid < FF){
    float a = 0.f;
    for (int k = 0; k < FF; ++k) a += vs[k] * W[k * FF + tid];
    rv[tid] = a;
  }
  // B fragments in registers: Bf[kchunk][coltile]; lane holds W[k=(q*32+(lane>>4)*8+j)][ct*16+(lane&15)]
  f16x8 Bf[4][2];
  int kg = (lane >> 4) * 8;
  int cl = lane & 15;
  #pragma unroll
  for (int q = 0; q < 4; ++q)
    #pragma unroll
    for (int ct = 0; ct < 2; ++ct){
      int col = (w * 2 + ct) * 16 + cl;
      #pragma unroll
      for (int j = 0; j < 8; ++j)
        Bf[q][ct][j] = (_Float16)W[(q * 32 + kg + j) * FF + col];
    }
  __syncthreads();

  for (int t = blockIdx.x; t < NTILES; t += gridDim.x){
    int base = t * 32;
    // stage A (f32 -> bn/relu -> f16)
    for (int i = tid; i < 32 * 32; i += 256){
      int r = i >> 5, cq = i & 31;
      float4 v = ((const float4*)(in + (size_t)(base + r) * FF))[cq];
      if (hasbn){
        int c0 = cq * 4;
        v.x = fmaxf(fmaf(v.x, scs[c0 + 0], shs[c0 + 0]), 0.f);
        v.y = fmaxf(fmaf(v.y, scs[c0 + 1], shs[c0 + 1]), 0.f);
        v.z = fmaxf(fmaf(v.z, scs[c0 + 2], shs[c0 + 2]), 0.f);
        v.w = fmaxf(fmaf(v.w, scs[c0 + 3], shs[c0 + 3]), 0.f);
      }
      _Float16* ap = &As[r * 136 + cq * 4];
      ap[0] = (_Float16)v.x; ap[1] = (_Float16)v.y;
      ap[2] = (_Float16)v.z; ap[3] = (_Float16)v.w;
    }
    __syncthreads();
    f32x4 acc[2][2] = {{{0,0,0,0},{0,0,0,0}},{{0,0,0,0},{0,0,0,0}}};
    #pragma unroll
    for (int q = 0; q < 4; ++q){
      f16x8 Af[2];
      #pragma unroll
      for (int rt = 0; rt < 2; ++rt)
        Af[rt] = *(const f16x8*)&As[(rt * 16 + cl) * 136 + q * 32 + kg];
      #pragma unroll
      for (int rt = 0; rt < 2; ++rt)
        #pragma unroll
        for (int ct = 0; ct < 2; ++ct)
          acc[rt][ct] = __builtin_amdgcn_mfma_f32_16x16x32_f16(Af[rt], Bf[q][ct], acc[rt][ct], 0, 0, 0);
    }
    // C -> LDS  (col = lane&15, row = (lane>>4)*4 + reg)
    #pragma unroll
    for (int rt = 0; rt < 2; ++rt)
      #pragma unroll
      for (int ct = 0; ct < 2; ++ct){
        int col = (w * 2 + ct) * 16 + cl;
        int r0 = rt * 16 + (lane >> 4) * 4;
        #pragma unroll
        for (int reg = 0; reg < 4; ++reg)
          Cs[(r0 + reg) * 132 + col] = acc[rt][ct][reg];
      }
    __syncthreads();
    // pack + store (add rv, scale dinv)
    for (int i = tid; i < 32 * 32; i += 256){
      int r = i >> 5, cq = i & 31;
      float d = dinv[base + r];
      float4 c = *(const float4*)&Cs[r * 132 + cq * 4];
      int c0 = cq * 4;
      float a0 = (c.x + rv[c0 + 0]) * d;
      float a1 = (c.y + rv[c0 + 1]) * d;
      float a2 = (c.z + rv[c0 + 2]) * d;
      float a3 = (c.w + rv[c0 + 3]) * d;
      __half2 h01 = __floats2half2_rn(a0, a1);
      __half2 h23 = __floats2half2_rn(a2, a3);
      uint2 pk;
      pk.x = *reinterpret_cast<unsigned int*>(&h01);
      pk.y = *reinterpret_cast<unsigned int*>(&h23);
      hlb[(size_t)(base + r) * 32 + cq] = pk;
    }
    __syncthreads();
  }
}

// ---------- wave-per-node CSR gather + BN stats (reg accum, unroll-8) ----------
__launch_bounds__(256)
__global__ void k_gather(const unsigned int* __restrict__ hlb, const float* __restrict__ dinv,
                         const int* __restrict__ offs, const int* __restrict__ ssorted,
                         float2* __restrict__ agg2, float* __restrict__ stats){
  int tid = threadIdx.x;
  int lane = tid & 63;
  int wid = (blockIdx.x * 256 + tid) >> 6;
  int nw = (gridDim.x * 256) >> 6;
  float s0 = 0.f, s1 = 0.f, q0 = 0.f, q1 = 0.f;
  for (int n = wid; n < NN; n += nw){
    int off0 = offs[n], off1 = offs[n + 1];
    unsigned int ps = hlb[(size_t)n * 64 + lane];   // self term (prescaled)
    float2 acc = __half22float2(*reinterpret_cast<__half2*>(&ps));
    #pragma unroll 8
    for (int e = off0; e < off1; ++e){
      unsigned int p = hlb[(size_t)ssorted[e] * 64 + lane];
      float2 f = __half22float2(*reinterpret_cast<__half2*>(&p));
      acc.x += f.x; acc.y += f.y;
    }
    float dv = dinv[n];
    float v0 = acc.x * dv, v1 = acc.y * dv;
    agg2[(size_t)n * 64 + lane] = make_float2(v0, v1);
    s0 += v0; s1 += v1; q0 += v0 * v0; q1 += v1 * v1;
  }
  __shared__ float4 red[256];
  red[tid] = make_float4(s0, s1, q0, q1);
  __syncthreads();
  if (tid < 64){
    float4 a = red[tid], b = red[tid + 64], c = red[tid + 128], d = red[tid + 192];
    a.x += b.x + c.x + d.x; a.y += b.y + c.y + d.y;
    a.z += b.z + c.z + d.z; a.w += b.w + c.w + d.w;
    atomicAdd(&stats[2 * tid], a.x);
    atomicAdd(&stats[2 * tid + 1], a.y);
    atomicAdd(&stats[FF + 2 * tid], a.z);
    atomicAdd(&stats[FF + 2 * tid + 1], a.w);
  }
}

// ---------- stats -> scale/shift ----------
__global__ void k_bnfin(const float* __restrict__ stats, const float* __restrict__ g,
                        const float* __restrict__ b, float* __restrict__ ss){
  int j = threadIdx.x;   // 128
  float mean = stats[j] * (1.0f / NN);
  float var  = stats[FF + j] * (1.0f / NN) - mean * mean;
  float sc = rsqrtf(var + EPSV) * g[j];
  ss[j] = sc;
  ss[FF + j] = b[j] - mean * sc;
}

// ---------- BN finalize + apply (final layer, no relu) ----------
__launch_bounds__(256)
__global__ void k_bnapply(float4* __restrict__ h, const float* __restrict__ stats,
                          const float* __restrict__ g, const float* __restrict__ b){
  __shared__ float ss[2 * FF];
  int tid = threadIdx.x;
  if (tid < FF){
    float mean = stats[tid] * (1.0f / NN);
    float var  = stats[FF + tid] * (1.0f / NN) - mean * mean;
    float sc = rsqrtf(var + EPSV) * g[tid];
    ss[tid] = sc;
    ss[FF + tid] = b[tid] - mean * sc;
  }
  __syncthreads();
  int n4 = NN * FF / 4;
  int stride = gridDim.x * 256;
  for (int i = blockIdx.x * 256 + tid; i < n4; i += stride){
    int c = (i & 31) * 4;
    float4 v = h[i];
    float4 sc = *(const float4*)&ss[c];
    float4 sh = *(const float4*)&ss[FF + c];
    v.x = v.x * sc.x + sh.x;
    v.y = v.y * sc.y + sh.y;
    v.z = v.z * sc.z + sh.z;
    v.w = v.w * sc.w + sh.w;
    h[i] = v;
  }
}

// ---------- pooled[v] = sum_{n: mask[v][n]} relu(bn(emb[n])) ----------
__global__ void k_pool(const float* __restrict__ emb, const unsigned char* __restrict__ m8,
                       const int* __restrict__ m32, const int* __restrict__ flag,
                       const float* __restrict__ ss, int hasbn,
                       float* __restrict__ pooled){
  int isb = *flag;
  int tid = blockIdx.x * 256 + threadIdx.x;
  int j = tid & 127;
  int r = tid >> 7;
  int rs = (gridDim.x * 256) >> 7;
  float sc = hasbn ? ss[j] : 1.0f;
  float sh = hasbn ? ss[FF + j] : 0.0f;
  float acc[VV];
  #pragma unroll
  for (int v = 0; v < VV; ++v) acc[v] = 0.f;
  for (; r < NN; r += rs){
    float xv = emb[r * FF + j];
    xv = fmaf(xv, sc, sh);
    if (hasbn) xv = fmaxf(xv, 0.f);
    #pragma unroll
    for (int v = 0; v < VV; ++v){
      int mv = isb ? (int)m8[v * NN + r] : m32[v * NN + r];
      if (mv) acc[v] += xv;
    }
  }
  #pragma unroll
  for (int v = 0; v < VV; ++v) atomicAdd(&pooled[v * FF + j], acc[v]);
}

// ---------- per-VN MLP ----------
__device__ __forceinline__ float blockSum(float x, float* red, int tid){
  red[tid] = x; __syncthreads();
  #pragma unroll
  for (int s = 128; s >= 1; s >>= 1){
    if (tid < s) red[tid] += red[tid + s];
    __syncthreads();
  }
  float r = red[0];
  __syncthreads();
  return r;
}

__launch_bounds__(256)
__global__ void k_vnmlp(const float* __restrict__ pooled, const float* __restrict__ vnin,
                        const float* __restrict__ W1, const float* __restrict__ b1,
                        const float* __restrict__ g1, const float* __restrict__ bb1,
                        const float* __restrict__ W2, const float* __restrict__ b2,
                        const float* __restrict__ g2, const float* __restrict__ bb2,
                        float* __restrict__ vnout){
  int v = blockIdx.x;
  int tid = threadIdx.x;
  __shared__ float tmp_s[FF];
  __shared__ float h1_s[F2];
  __shared__ float red[256];
  if (tid < FF) tmp_s[tid] = pooled[v * FF + tid] + vnin[v * FF + tid];
  __syncthreads();
  const float* W1v = W1 + (size_t)v * FF * F2;
  float acc = b1[v * F2 + tid];
  for (int k = 0; k < FF; ++k) acc += tmp_s[k] * W1v[k * F2 + tid];
  acc = fmaxf(acc, 0.f);
  float sum = blockSum(acc, red, tid);
  float sq  = blockSum(acc * acc, red, tid);
  float mean = sum * (1.f / F2);
  float var  = sq * (1.f / F2) - mean * mean;
  float y = (acc - mean) * rsqrtf(var + EPSV) * g1[v * F2 + tid] + bb1[v * F2 + tid];
  h1_s[tid] = y;
  __syncthreads();
  const float* W2v = W2 + (size_t)v * F2 * FF;
  float h2 = 0.f;
  if (tid < FF){
    float a2 = b2[v * FF + tid];
    for (int k = 0; k < F2; ++k) a2 += h1_s[k] * W2v[k * FF + tid];
    h2 = fmaxf(a2, 0.f);
  }
  float sum2 = blockSum((tid < FF) ? h2 : 0.f, red, tid);
  float sq2  = blockSum((tid < FF) ? h2 * h2 : 0.f, red, tid);
  float mean2 = sum2 * (1.f / FF);
  float var2  = sq2 * (1.f / FF) - mean2 * mean2;
  if (tid < FF)
    vnout[v * FF + tid] = (h2 - mean2) * rsqrtf(var2 + EPSV) * g2[v * FF + tid]
                          + bb2[v * FF + tid];
}

extern "C" void kernel_launch(void* const* d_in, const int* in_sizes, int n_in,
                              void* d_out, int out_size, void* d_ws, size_t ws_size,
                              hipStream_t stream){
  const float* x        = (const float*)d_in[0];
  const int*   ei       = (const int*)d_in[1];
  const unsigned char* vmask8 = (const unsigned char*)d_in[2];
  const int*   vmask32  = (const int*)d_in[2];
  const float* Wc       = (const float*)d_in[3];
  const float* bn_g     = (const float*)d_in[5];
  const float* bn_b     = (const float*)d_in[6];
  const float* vn_embed = (const float*)d_in[7];
  const float* mlp_W1   = (const float*)d_in[8];
  const float* mlp_b1   = (const float*)d_in[9];
  const float* ln1_g    = (const float*)d_in[10];
  const float* ln1_b    = (const float*)d_in[11];
  const float* mlp_W2   = (const float*)d_in[12];
  const float* mlp_b2   = (const float*)d_in[13];
  const float* ln2_g    = (const float*)d_in[14];
  const float* ln2_b    = (const float*)d_in[15];
  float* out = (float*)d_out;

  unsigned int* hlb = (unsigned int*)d_ws;               // N*64 u32 (fp16x2) = 25.6MB
  float* bufB    = (float*)(hlb + (size_t)NN * 64);      // N*F f32
  int*   ssorted = (int*)(bufB + (size_t)NN * FF);       // E
  int*   offs    = ssorted + EE;                         // N+1
  int*   cursor  = offs + NN + 1;                        // N
  int*   edeg    = cursor + NN;                          // N
  int*   bsum    = edeg + NN;                            // 128
  float* dinv    = (float*)(bsum + 128);                 // N
  float* stats   = dinv + NN;                            // 2F
  float* ssA     = stats + 2 * FF;                       // 2F
  float* ssB     = ssA + 2 * FF;                         // 2F
  float* pooled  = ssB + 2 * FF;                         // V*F
  float* vnA     = pooled + VV * FF;                     // V*F
  float* vnB     = vnA + VV * FF;                        // V*F
  int*   mflag   = (int*)(vnB + VV * FF);                // 1

  const int* esrc = ei;
  const int* edst = ei + EE;

  // ----- CSR build -----
  hipMemsetAsync(edeg, 0, NN * sizeof(int), stream);
  k_deg<<<1024, 256, 0, stream>>>(edst, edeg);
  k_scanA<<<NB, 1024, 0, stream>>>(edeg, offs, bsum, dinv);
  k_scanB<<<1, 128, 0, stream>>>(bsum);
  k_scanC<<<idiv(NN, 256), 256, 0, stream>>>(offs, bsum, cursor);
  k_scatter<<<2048, 256, 0, stream>>>(esrc, edst, cursor, ssorted);

  hipMemsetAsync(mflag, 0, sizeof(int), stream);
  k_maskdetect<<<1, 256, 0, stream>>>(vmask8, mflag);

  const float* vncur = vn_embed;
  const float* embin = x;
  float* ssbufs[2] = {ssA, ssB};
  const float* sscur = nullptr;
  float* vnbufs[2] = {vnA, vnB};

  for (int l = 0; l < LL; ++l){
    float* agg = (l < LL - 1) ? bufB : out;
    const float* Wl = Wc + (size_t)l * FF * FF;
    int hasbn = (l > 0) ? 1 : 0;

    k_matmul<<<1024, 256, 0, stream>>>(embin, Wl, vncur, dinv, sscur, hasbn, (uint2*)hlb);

    if (l < LL - 1){
      hipMemsetAsync(pooled, 0, VV * FF * sizeof(float), stream);
      k_pool<<<1024, 256, 0, stream>>>(embin, vmask8, vmask32, mflag, sscur, hasbn, pooled);
    }

    hipMemsetAsync(stats, 0, 2 * FF * sizeof(float), stream);
    k_gather<<<2048, 256, 0, stream>>>(hlb, dinv, offs, ssorted, (float2*)agg, stats);

    if (l < LL - 1){
      k_bnfin<<<1, 128, 0, stream>>>(stats, bn_g + l * FF, bn_b + l * FF, ssbufs[l]);
      k_vnmlp<<<VV, 256, 0, stream>>>(pooled, vncur,
          mlp_W1 + (size_t)l * VV * FF * F2, mlp_b1 + (size_t)l * VV * F2,
          ln1_g + (size_t)l * VV * F2, ln1_b + (size_t)l * VV * F2,
          mlp_W2 + (size_t)l * VV * F2 * FF, mlp_b2 + (size_t)l * VV * FF,
          ln2_g + (size_t)l * VV * FF, ln2_b + (size_t)l * VV * FF,
          vnbufs[l]);
      vncur = vnbufs[l];
      sscur = ssbufs[l];
      embin = agg;
    } else {
      k_bnapply<<<1024, 256, 0, stream>>>((float4*)out, stats, bn_g + l * FF, bn_b + l * FF);
    }
  }
}